// Round 17
// baseline (101.503 us; speedup 1.0000x reference)
//
#include <hip/hip_runtime.h>
#include <hip/hip_bf16.h>

// DenseGraphSimpleOpEdgeFlow — R17: R16's 24-waves/CU structure, made spill-free.
// R16 proved 3 blocks/CU is reachable ((512,6) -> 64% occupancy) but the ~88-VGPR body
// overflowed the 85-reg cap (VGPR_Count 40, WRITE 3->57MB scratch). This round packs sfrag
// as bf16 pairs (24 float VGPRs -> 12 uint; RNE pack once per block, shift/mask unpack at
// use; residual still reads fp32 S2) so the body fits ~76 regs under the (512,6) cap.
// Keeps R16's 2-barrier pipeline: {issue g+1 | deferred store g-1 | convert}{lgkm0+BAR-A}
// {MFMA+sigmoid+publish}{vmcnt0+lgkm0+BAR-B}. 49th-K mask fold (d48; attn=rcp(1+exp2(acc))),
// bias in C-init, wave-contiguous S2, XOR-swizzled Atile, global_load_lds dbuf.
// Requires ws_size >= 64*96*128*4 = 3,145,728 bytes (S2 scratch).

#define B_ 64
#define N_ 96
#define F_ 128
#define D_ 48
#define G_ 8
#define NGRP (N_ / G_)   // 12 groups per b -> grid = 64*12 = 768 blocks = 3/CU

typedef __attribute__((ext_vector_type(8))) short short8;
typedef __attribute__((ext_vector_type(4))) float f32x4;

#if __has_builtin(__builtin_amdgcn_exp2f)
#define EXP2(x) __builtin_amdgcn_exp2f(x)
#else
#define EXP2(x) exp2f(x)
#endif

__device__ __forceinline__ void gload_lds16(const void* g, void* l) {
    __builtin_amdgcn_global_load_lds(
        (const __attribute__((address_space(1))) void*)g,
        (__attribute__((address_space(3))) void*)l, 16, 0, 0);
}

// S2 layout (wave-contiguous reads): float2 index (((b*6 + mt)*4 + r)*4 + lg)*64 + fbp
__device__ __forceinline__ size_t s2i(int b, int mt, int r, int lg, int fbp) {
    return ((((size_t)b * 6 + mt) * 4 + r) * 4 + lg) * 64 + fbp;
}

__device__ __forceinline__ unsigned bfbits(float x) {
    union { __hip_bfloat16 h; unsigned short u; } cv;
    cv.h = __float2bfloat16(x);
    return (unsigned)cv.u;
}
__device__ __forceinline__ float frombits(unsigned u) {
    union { unsigned v; float f; } cv;
    cv.v = u;
    return cv.f;
}

// ---------------- Kernel 1: support = inputs @ weight, written in S2 fragment layout ----------------
__global__ __launch_bounds__(256, 4) void support_kernel(
    const float* __restrict__ inputs, const float* __restrict__ weight,
    float2* __restrict__ S2)
{
    __shared__ float in_lds[16 * F_];
    const int tid = threadIdx.x;
    const int row0 = blockIdx.x * 16;
    ((float4*)in_lds)[tid]       = ((const float4*)(inputs + (size_t)row0 * F_))[tid];
    ((float4*)in_lds)[tid + 256] = ((const float4*)(inputs + (size_t)row0 * F_))[tid + 256];
    __syncthreads();
    const int rl = tid >> 4, f0 = (tid & 15) * 8;
    float acc[8] = {0.f,0.f,0.f,0.f,0.f,0.f,0.f,0.f};
    #pragma unroll 4
    for (int k = 0; k < F_; ++k) {
        const float a = in_lds[rl * F_ + k];
        const float4 w0 = *(const float4*)(weight + k * F_ + f0);
        const float4 w1 = *(const float4*)(weight + k * F_ + f0 + 4);
        acc[0] += a * w0.x; acc[1] += a * w0.y; acc[2] += a * w0.z; acc[3] += a * w0.w;
        acc[4] += a * w1.x; acc[5] += a * w1.y; acc[6] += a * w1.z; acc[7] += a * w1.w;
    }
    const int R = row0 + rl;
    const int b = R / N_, j = R - b * N_;
    const int mt = j >> 4, lg = (j >> 2) & 3, r = j & 3;
    #pragma unroll
    for (int q = 0; q < 4; ++q) {
        const int fbp = (f0 >> 1) + q;   // f-pair index
        S2[s2i(b, mt, r, lg, fbp)] = make_float2(acc[2 * q], acc[2 * q + 1]);
    }
}

// ---------------- Kernel 2: fused attn-GEMM, pipelined, 8 waves = (4 f-slices) x (2 mt-halves) ----------------
// MFMA 16x16x32 k-slot fill d = ks*32 + (lane>>4)*8 + e, identical for A and B (physical-k
// permutation cancels). C/D (HW-verified): col = lane&15 (-> f-pair), row = (lane>>4)*4+reg (-> j).
__global__ __launch_bounds__(512, 6) void fused_kernel(
    const float* __restrict__ op_emb,
    const unsigned* __restrict__ adjw,      // raw 32-bit view of adj (int32 or int64)
    const float* __restrict__ attn_w,
    const float* __restrict__ attn_b,
    const float* __restrict__ self_op,
    const float2* __restrict__ S2,
    float* __restrict__ out)
{
    __shared__ __align__(16) float F32buf[2][N_ * D_];       // 2 x 18,432 B raw fp32 tiles
    __shared__ __align__(16) unsigned short Atile[N_ * 64];  // 12,288 B bf16; d=48 mask slot
    __shared__ __align__(8)  float2 Ppart[2][4][16];         // wj=1 partials, double-buffered

    const int tid  = threadIdx.x;
    const int lane = tid & 63;
    const int wid  = tid >> 6;      // wave 0..7
    const int wf   = wid & 3;       // f-slice
    const int wj   = wid >> 2;      // mt-half: mt in [3*wj, 3*wj+3)
    const int lg   = lane >> 4;
    const int lm   = lane & 15;
    const int fb   = wf * 32 + lm * 2;
    const int fbp  = wf * 16 + lm;

    const int blk = blockIdx.x;
    const int b   = blk / NGRP;
    const int grp = blk - b * NGRP;
    const int i0  = grp * G_;

    const float kNL2E = -1.44269504088896f;

    // --- adj dtype sniff: int64 little-endian has all-zero high words (values 0..4) ---
    const unsigned probe = adjw[2 * lane + 1];
    const bool use32 = __any(probe != 0);

    // issue the 18 x 1KB direct-to-LDS copies for tile i -> F32buf[pb] (fire-and-forget)
    auto issue_tile = [&](int i, int pb) {
        const char* gbase = (const char*)(op_emb + (size_t)(b * N_ + i) * N_ * D_);
        char* lbase = (char*)(&F32buf[pb][0]);
        #pragma unroll
        for (int c0 = 0; c0 < 3; ++c0) {
            const int c = wid + 8 * c0;
            if (c < 18) gload_lds16(gbase + c * 1024 + lane * 16, lbase + c * 1024);
        }
    };
    auto load_adj = [&](int i) -> int {
        int a = 0;
        if (tid < N_) {
            const size_t idx = (size_t)(b * N_ + i) * N_ + tid;
            a = use32 ? (int)adjw[idx] : (int)adjw[2 * idx];
            a += (tid == i) ? 1 : 0;
        }
        return a;
    };

    // ---- prologue: issue tile 0 + adj row 0 (latency overlaps the preamble below) ----
    issue_tile(i0, 0);
    int adjreg = load_adj(i0);

    // --- B fragments (attn_w pre-scaled by -log2e; d==48 -> 1.0) + bias ---
    short8 bfrag[2][2];
    float  bbias[2];
    {
        const float2 bb = *(const float2*)(attn_b + fb);
        bbias[0] = bb.x * kNL2E;
        bbias[1] = bb.y * kNL2E;
        #pragma unroll
        for (int ks = 0; ks < 2; ++ks) {
            short8 v0, v1;
            #pragma unroll
            for (int e = 0; e < 8; ++e) {
                const int d = ks * 32 + lg * 8 + e;
                if (d < D_) {
                    const float2 w = *(const float2*)(attn_w + d * F_ + fb);
                    v0[e] = (short)bfbits(w.x * kNL2E);
                    v1[e] = (short)bfbits(w.y * kNL2E);
                } else {
                    const unsigned one = (d == D_) ? bfbits(1.0f) : 0u;
                    v0[e] = (short)one;
                    v1[e] = (short)one;
                }
            }
            bfrag[0][ks] = v0;
            bfrag[1][ks] = v1;
        }
    }

    // --- support fragments for THIS wave's mt-half, PACKED bf16 (12 VGPRs, was 24) ---
    unsigned sfp[3][4];
    #pragma unroll
    for (int s = 0; s < 3; ++s)
        #pragma unroll
        for (int r = 0; r < 4; ++r) {
            const float2 v = S2[s2i(b, 3 * wj + s, r, lg, fbp)];
            sfp[s][r] = bfbits(v.x) | (bfbits(v.y) << 16);   // RNE bf16 pack
        }

    // --- zero Atile k-pad d in [50,64) once per block ---
    for (int v = tid; v < N_ * 7; v += 512) {
        const int j = v / 7, q = v - 7 * j;
        const int byte = j * 128 + ((100 + q * 4) ^ ((j & 7) << 4));
        *(unsigned*)((char*)Atile + byte) = 0u;
    }

    __syncthreads();   // full drain once per block: tile-0 loads + pad writes visible

    float osum_prev0 = 0.f, osum_prev1 = 0.f;

    #pragma unroll 1
    for (int g = 0; g < G_; ++g) {
        const int cur = g & 1;
        const int i = i0 + g;

        // ---- P1a: issue next tile's loads (stay in flight across the barriers) ----
        int adjnext = 0;
        if (g + 1 < G_) {
            issue_tile(i + 1, cur ^ 1);
            adjnext = load_adj(i + 1);
        }

        // ---- P1b: deferred store of tile g-1 (Ppart visible since BAR-B of g-1) ----
        if (g > 0 && wj == 0 && lg == 0) {
            const int ip = i - 1;
            const float2 pp = Ppart[(g - 1) & 1][wf][lm];
            const float2 sr = S2[s2i(b, ip >> 4, ip & 3, (ip >> 2) & 3, fbp)];
            float2 o;
            o.x = osum_prev0 + pp.x + sr.x;
            o.y = osum_prev1 + pp.y + sr.y;
            *(float2*)(out + (size_t)(b * N_ + ip) * F_ + fb) = o;
        }

        // ---- P1c: convert F32buf[cur] -> bf16 swizzled Atile; row i <- self_op; d48 <- off ----
        #pragma unroll
        for (int s = 0; s < 3; ++s) {
            const int w = tid + s * 512;
            if (w < N_ * 12) {
                const int j = w / 12, c = w - 12 * j;
                float4 p;
                if (j == i) p = *(const float4*)(self_op + c * 4);
                else        p = *(const float4*)((const char*)(&F32buf[cur][0]) + 16 * w);
                const int byte = j * 128 + ((c * 8) ^ ((j & 7) << 4));
                *(uint2*)((char*)Atile + byte) =
                    make_uint2(bfbits(p.x) | (bfbits(p.y) << 16),
                               bfbits(p.z) | (bfbits(p.w) << 16));
            }
        }
        if (tid < N_) {
            // mask slot d=48: a'==0 -> +126 (attn 0 via exp2 saturation), a'==1 -> -126, else 0
            const float off = (adjreg == 0) ? 126.f : ((adjreg == 1) ? -126.f : 0.f);
            const int byte = tid * 128 + (96 ^ ((tid & 7) << 4));
            *(unsigned*)((char*)Atile + byte) = bfbits(off);
        }
        asm volatile("s_waitcnt lgkmcnt(0)" ::: "memory");  // Atile writes visible
        __builtin_amdgcn_s_barrier();                       // BAR-A (no vmcnt drain)

        // ---- P2: this wave's 3 mt-slabs; attn = rcp(1 + exp2(acc)) ----
        float osum0 = 0.f, osum1 = 0.f;
        #pragma unroll
        for (int s = 0; s < 3; ++s) {
            const int mt  = 3 * wj + s;
            const int jr  = mt * 16 + lm;
            const int swz = (lm & 7) << 4;
            const char* base = (const char*)Atile + jr * 128;
            const short8 a0 = *(const short8*)(base + (( 0 + lg * 16) ^ swz));
            const short8 a1 = *(const short8*)(base + ((64 + lg * 16) ^ swz));
            f32x4 c0 = (f32x4){bbias[0], bbias[0], bbias[0], bbias[0]};
            f32x4 c1 = (f32x4){bbias[1], bbias[1], bbias[1], bbias[1]};
            c0 = __builtin_amdgcn_mfma_f32_16x16x32_bf16(a0, bfrag[0][0], c0, 0, 0, 0);
            c0 = __builtin_amdgcn_mfma_f32_16x16x32_bf16(a1, bfrag[0][1], c0, 0, 0, 0);
            c1 = __builtin_amdgcn_mfma_f32_16x16x32_bf16(a0, bfrag[1][0], c1, 0, 0, 0);
            c1 = __builtin_amdgcn_mfma_f32_16x16x32_bf16(a1, bfrag[1][1], c1, 0, 0, 0);
            #pragma unroll
            for (int r = 0; r < 4; ++r) {
                const float s0 = __builtin_amdgcn_rcpf(1.f + EXP2(c0[r]));
                const float s1 = __builtin_amdgcn_rcpf(1.f + EXP2(c1[r]));
                const unsigned p = sfp[s][r];
                osum0 = __builtin_fmaf(s0, frombits(p << 16), osum0);
                osum1 = __builtin_fmaf(s1, frombits(p & 0xffff0000u), osum1);
            }
        }
        // reduce over the 4 lg j-subsets within the wave
        osum0 += __shfl_xor(osum0, 16);
        osum0 += __shfl_xor(osum0, 32);
        osum1 += __shfl_xor(osum1, 16);
        osum1 += __shfl_xor(osum1, 32);
        // wj=1 publishes its half (consumed next iteration, after BAR-B)
        if (wj == 1 && lg == 0)
            Ppart[g & 1][wf][lm] = make_float2(osum0, osum1);
        osum_prev0 = osum0;
        osum_prev1 = osum1;

        // ---- BAR-B: next-tile loads landed + Ppart visible; releases Atile/F32buf ----
        asm volatile("s_waitcnt vmcnt(0) lgkmcnt(0)" ::: "memory");
        __builtin_amdgcn_s_barrier();
        adjreg = adjnext;
    }

    // ---- epilogue: store the last tile ----
    if (wj == 0 && lg == 0) {
        const int ip = i0 + G_ - 1;
        const float2 pp = Ppart[(G_ - 1) & 1][wf][lm];
        const float2 sr = S2[s2i(b, ip >> 4, ip & 3, (ip >> 2) & 3, fbp)];
        float2 o;
        o.x = osum_prev0 + pp.x + sr.x;
        o.y = osum_prev1 + pp.y + sr.y;
        *(float2*)(out + (size_t)(b * N_ + ip) * F_ + fb) = o;
    }
}

extern "C" void kernel_launch(void* const* d_in, const int* in_sizes, int n_in,
                              void* d_out, int out_size, void* d_ws, size_t ws_size,
                              hipStream_t stream) {
    const float*    inputs  = (const float*)d_in[0];
    const unsigned* adjw    = (const unsigned*)d_in[1];
    const float*    op_emb  = (const float*)d_in[2];
    const float*    weight  = (const float*)d_in[3];
    const float*    attn_w  = (const float*)d_in[4];
    const float*    attn_b  = (const float*)d_in[5];
    const float*    self_op = (const float*)d_in[6];
    float* out = (float*)d_out;
    float2* S2 = (float2*)d_ws;  // fragment-layout support, 3,145,728 bytes

    support_kernel<<<(B_ * N_) / 16, 256, 0, stream>>>(inputs, weight, S2);
    fused_kernel<<<B_ * NGRP, 512, 0, stream>>>(op_emb, adjw, attn_w, attn_b, self_op,
                                                S2, out);
}

// Round 18
// 61.918 us; speedup vs baseline: 1.6393x; 1.6393x over previous
//
#include <hip/hip_runtime.h>
#include <hip/hip_bf16.h>

// DenseGraphSimpleOpEdgeFlow — R18: R15's (512,4) config + 2-deep counted-vmcnt pipeline.
// R16/R17: (.,6) VGPR cap 85 < body's ~88 -> catastrophic spill twice; 24w/CU is a dead end.
// R15 (16w/CU, 1-deep, vmcnt(0)/tile) = 61.5us best. This round keeps (512,4) and removes
// the per-tile full drain: 3 F32 buffers, 2-tile lookahead, every wave issues EXACTLY 3
// global_load_lds per tile (tail re-issues clamped) so s_waitcnt vmcnt(6) retires tile-g's
// loads while g+1/g+2 stay in flight (T4). adj mask offsets precomputed to LDS (moff) in the
// prologue so loop VMEM = loads + deferred store only. 2 barriers/tile (R16 merge, proven).
// Keeps: 49th-K mask fold (d48; attn=rcp(1+exp2(acc))), bias in C-init, wave-contiguous S2,
// XOR-swizzled Atile, fp32 sfrag (fits under cap 128).
// Requires ws_size >= 64*96*128*4 = 3,145,728 bytes (S2 scratch).

#define B_ 64
#define N_ 96
#define F_ 128
#define D_ 48
#define G_ 12
#define NGRP (N_ / G_)   // 8 groups per b -> grid = 64*8 = 512 blocks = 2/CU

typedef __attribute__((ext_vector_type(8))) short short8;
typedef __attribute__((ext_vector_type(4))) float f32x4;

#if __has_builtin(__builtin_amdgcn_exp2f)
#define EXP2(x) __builtin_amdgcn_exp2f(x)
#else
#define EXP2(x) exp2f(x)
#endif

__device__ __forceinline__ void gload_lds16(const void* g, void* l) {
    __builtin_amdgcn_global_load_lds(
        (const __attribute__((address_space(1))) void*)g,
        (__attribute__((address_space(3))) void*)l, 16, 0, 0);
}

// S2 layout (wave-contiguous reads): float2 index (((b*6 + mt)*4 + r)*4 + lg)*64 + fbp
__device__ __forceinline__ size_t s2i(int b, int mt, int r, int lg, int fbp) {
    return ((((size_t)b * 6 + mt) * 4 + r) * 4 + lg) * 64 + fbp;
}

__device__ __forceinline__ unsigned bfbits(float x) {
    union { __hip_bfloat16 h; unsigned short u; } cv;
    cv.h = __float2bfloat16(x);
    return (unsigned)cv.u;
}

// ---------------- Kernel 1: support = inputs @ weight, written in S2 fragment layout ----------------
__global__ __launch_bounds__(256, 4) void support_kernel(
    const float* __restrict__ inputs, const float* __restrict__ weight,
    float2* __restrict__ S2)
{
    __shared__ float in_lds[16 * F_];
    const int tid = threadIdx.x;
    const int row0 = blockIdx.x * 16;
    ((float4*)in_lds)[tid]       = ((const float4*)(inputs + (size_t)row0 * F_))[tid];
    ((float4*)in_lds)[tid + 256] = ((const float4*)(inputs + (size_t)row0 * F_))[tid + 256];
    __syncthreads();
    const int rl = tid >> 4, f0 = (tid & 15) * 8;
    float acc[8] = {0.f,0.f,0.f,0.f,0.f,0.f,0.f,0.f};
    #pragma unroll 4
    for (int k = 0; k < F_; ++k) {
        const float a = in_lds[rl * F_ + k];
        const float4 w0 = *(const float4*)(weight + k * F_ + f0);
        const float4 w1 = *(const float4*)(weight + k * F_ + f0 + 4);
        acc[0] += a * w0.x; acc[1] += a * w0.y; acc[2] += a * w0.z; acc[3] += a * w0.w;
        acc[4] += a * w1.x; acc[5] += a * w1.y; acc[6] += a * w1.z; acc[7] += a * w1.w;
    }
    const int R = row0 + rl;
    const int b = R / N_, j = R - b * N_;
    const int mt = j >> 4, lg = (j >> 2) & 3, r = j & 3;
    #pragma unroll
    for (int q = 0; q < 4; ++q) {
        const int fbp = (f0 >> 1) + q;   // f-pair index
        S2[s2i(b, mt, r, lg, fbp)] = make_float2(acc[2 * q], acc[2 * q + 1]);
    }
}

// ---------------- Kernel 2: fused attn-GEMM, 2-deep pipelined, 8 waves = (4 f) x (2 mt-halves) ----------------
// MFMA 16x16x32 k-slot fill d = ks*32 + (lane>>4)*8 + e, identical for A and B (physical-k
// permutation cancels). C/D (HW-verified): col = lane&15 (-> f-pair), row = (lane>>4)*4+reg (-> j).
__global__ __launch_bounds__(512, 4) void fused_kernel(
    const float* __restrict__ op_emb,
    const unsigned* __restrict__ adjw,      // raw 32-bit view of adj (int32 or int64)
    const float* __restrict__ attn_w,
    const float* __restrict__ attn_b,
    const float* __restrict__ self_op,
    const float2* __restrict__ S2,
    float* __restrict__ out)
{
    __shared__ __align__(16) float F32buf[3][N_ * D_];       // 3 x 18,432 B raw fp32 tiles
    __shared__ __align__(16) unsigned short Atile[N_ * 64];  // 12,288 B bf16; d=48 mask slot
    __shared__ __align__(8)  float2 Ppart[2][4][16];         // wj=1 partials, double-buffered
    __shared__ unsigned short moff[G_][N_];                  // bf16 bits of mask offsets

    const int tid  = threadIdx.x;
    const int lane = tid & 63;
    const int wid  = tid >> 6;      // wave 0..7
    const int wf   = wid & 3;       // f-slice
    const int wj   = wid >> 2;      // mt-half: mt in [3*wj, 3*wj+3)
    const int lg   = lane >> 4;
    const int lm   = lane & 15;
    const int fb   = wf * 32 + lm * 2;
    const int fbp  = wf * 16 + lm;

    const int blk = blockIdx.x;
    const int b   = blk / NGRP;
    const int grp = blk - b * NGRP;
    const int i0  = grp * G_;

    const float kNL2E = -1.44269504088896f;

    // --- adj dtype sniff: int64 little-endian has all-zero high words (values 0..4) ---
    const unsigned probe = adjw[2 * lane + 1];
    const bool use32 = __any(probe != 0);

    // issue EXACTLY 3 direct-to-LDS 1KB copies per wave for tile i -> F32buf[pb]
    // (chunks c>17 clamp to 17: duplicate identical writes, keeps vmcnt uniform)
    auto issue_tile = [&](int i, int pb) {
        const char* gbase = (const char*)(op_emb + (size_t)(b * N_ + i) * N_ * D_);
        char* lbase = (char*)(&F32buf[pb][0]);
        #pragma unroll
        for (int c0 = 0; c0 < 3; ++c0) {
            int c = wid + 8 * c0;
            c = (c < 18) ? c : 17;
            gload_lds16(gbase + c * 1024 + lane * 16, lbase + c * 1024);
        }
    };

    // ---- prologue: issue tiles 0,1 + precompute mask offsets + preamble loads ----
    issue_tile(i0, 0);
    issue_tile(i0 + 1, 1);

    #pragma unroll 1
    for (int g = 0; g < G_; ++g) {
        if (tid < N_) {
            const int i = i0 + g;
            const size_t idx = (size_t)(b * N_ + i) * N_ + tid;
            int a = use32 ? (int)adjw[idx] : (int)adjw[2 * idx];
            a += (tid == i) ? 1 : 0;
            // a'==0 -> +126 (attn 0 via exp2 saturation), a'==1 -> -126 (attn 1), else 0
            const float off = (a == 0) ? 126.f : ((a == 1) ? -126.f : 0.f);
            moff[g][tid] = (unsigned short)bfbits(off);
        }
    }

    // --- B fragments (attn_w pre-scaled by -log2e; d==48 -> 1.0) + bias ---
    short8 bfrag[2][2];
    float  bbias[2];
    {
        const float2 bb = *(const float2*)(attn_b + fb);
        bbias[0] = bb.x * kNL2E;
        bbias[1] = bb.y * kNL2E;
        #pragma unroll
        for (int ks = 0; ks < 2; ++ks) {
            short8 v0, v1;
            #pragma unroll
            for (int e = 0; e < 8; ++e) {
                const int d = ks * 32 + lg * 8 + e;
                if (d < D_) {
                    const float2 w = *(const float2*)(attn_w + d * F_ + fb);
                    v0[e] = (short)bfbits(w.x * kNL2E);
                    v1[e] = (short)bfbits(w.y * kNL2E);
                } else {
                    const unsigned one = (d == D_) ? bfbits(1.0f) : 0u;
                    v0[e] = (short)one;
                    v1[e] = (short)one;
                }
            }
            bfrag[0][ks] = v0;
            bfrag[1][ks] = v1;
        }
    }

    // --- support fragments for THIS wave's mt-half (fp32, 24 regs; cap is 128) ---
    float2 sfrag[3][4];
    #pragma unroll
    for (int s = 0; s < 3; ++s)
        #pragma unroll
        for (int r = 0; r < 4; ++r)
            sfrag[s][r] = S2[s2i(b, 3 * wj + s, r, lg, fbp)];

    // --- zero Atile k-pad d in [50,64) once per block ---
    for (int v = tid; v < N_ * 7; v += 512) {
        const int j = v / 7, q = v - 7 * j;
        const int byte = j * 128 + ((100 + q * 4) ^ ((j & 7) << 4));
        *(unsigned*)((char*)Atile + byte) = 0u;
    }

    __syncthreads();   // full drain ONCE per block: tiles 0,1 + moff + pads all visible

    float osum_prev0 = 0.f, osum_prev1 = 0.f;

    #pragma unroll 1
    for (int g = 0; g < G_; ++g) {
        const int i = i0 + g;

        // ---- P0: issue tile g+2's loads (clamped at tail; uniform 3/wave always) ----
        {
            const int inext = i0 + ((g + 2 < G_) ? (g + 2) : (G_ - 1));
            issue_tile(inext, (g + 2) % 3);
        }

        // ---- W: retire tile-g's loads (g+1, g+2 stay in flight); Ppart(g-1) visible ----
        asm volatile("s_waitcnt vmcnt(6) lgkmcnt(0)" ::: "memory");
        __builtin_amdgcn_s_barrier();

        // ---- P1: deferred store of tile g-1 ----
        if (g > 0 && wj == 0 && lg == 0) {
            const int ip = i - 1;
            const float2 pp = Ppart[(g - 1) & 1][wf][lm];
            const float2 sr = S2[s2i(b, ip >> 4, ip & 3, (ip >> 2) & 3, fbp)];
            float2 o;
            o.x = osum_prev0 + pp.x + sr.x;
            o.y = osum_prev1 + pp.y + sr.y;
            *(float2*)(out + (size_t)(b * N_ + ip) * F_ + fb) = o;
        }

        // ---- P2: convert F32buf[g%3] -> bf16 swizzled Atile; row i <- self_op; d48 <- moff ----
        {
            const float* fsrc = &F32buf[g % 3][0];
            #pragma unroll
            for (int s = 0; s < 3; ++s) {
                const int w = tid + s * 512;
                if (w < N_ * 12) {
                    const int j = w / 12, c = w - 12 * j;
                    float4 p;
                    if (j == i) p = *(const float4*)(self_op + c * 4);
                    else        p = *(const float4*)((const char*)fsrc + 16 * w);
                    const int byte = j * 128 + ((c * 8) ^ ((j & 7) << 4));
                    *(uint2*)((char*)Atile + byte) =
                        make_uint2(bfbits(p.x) | (bfbits(p.y) << 16),
                                   bfbits(p.z) | (bfbits(p.w) << 16));
                }
            }
            if (tid < N_) {
                const int byte = tid * 128 + (96 ^ ((tid & 7) << 4));
                *(unsigned*)((char*)Atile + byte) = (unsigned)moff[g][tid];
            }
        }
        asm volatile("s_waitcnt lgkmcnt(0)" ::: "memory");  // Atile writes visible
        __builtin_amdgcn_s_barrier();                       // BAR-B (no vmcnt drain)

        // ---- P3: this wave's 3 mt-slabs; attn = rcp(1 + exp2(acc)) ----
        float osum0 = 0.f, osum1 = 0.f;
        #pragma unroll
        for (int s = 0; s < 3; ++s) {
            const int mt  = 3 * wj + s;
            const int jr  = mt * 16 + lm;
            const int swz = (lm & 7) << 4;
            const char* base = (const char*)Atile + jr * 128;
            const short8 a0 = *(const short8*)(base + (( 0 + lg * 16) ^ swz));
            const short8 a1 = *(const short8*)(base + ((64 + lg * 16) ^ swz));
            f32x4 c0 = (f32x4){bbias[0], bbias[0], bbias[0], bbias[0]};
            f32x4 c1 = (f32x4){bbias[1], bbias[1], bbias[1], bbias[1]};
            c0 = __builtin_amdgcn_mfma_f32_16x16x32_bf16(a0, bfrag[0][0], c0, 0, 0, 0);
            c0 = __builtin_amdgcn_mfma_f32_16x16x32_bf16(a1, bfrag[0][1], c0, 0, 0, 0);
            c1 = __builtin_amdgcn_mfma_f32_16x16x32_bf16(a0, bfrag[1][0], c1, 0, 0, 0);
            c1 = __builtin_amdgcn_mfma_f32_16x16x32_bf16(a1, bfrag[1][1], c1, 0, 0, 0);
            #pragma unroll
            for (int r = 0; r < 4; ++r) {
                const float s0 = __builtin_amdgcn_rcpf(1.f + EXP2(c0[r]));
                const float s1 = __builtin_amdgcn_rcpf(1.f + EXP2(c1[r]));
                osum0 = __builtin_fmaf(s0, sfrag[s][r].x, osum0);
                osum1 = __builtin_fmaf(s1, sfrag[s][r].y, osum1);
            }
        }
        // reduce over the 4 lg j-subsets within the wave
        osum0 += __shfl_xor(osum0, 16);
        osum0 += __shfl_xor(osum0, 32);
        osum1 += __shfl_xor(osum1, 16);
        osum1 += __shfl_xor(osum1, 32);
        // wj=1 publishes its half (consumed next iteration after W, or in epilogue)
        if (wj == 1 && lg == 0)
            Ppart[g & 1][wf][lm] = make_float2(osum0, osum1);
        osum_prev0 = osum0;
        osum_prev1 = osum1;
    }

    // ---- epilogue: make last Ppart visible, store the last tile ----
    asm volatile("s_waitcnt lgkmcnt(0)" ::: "memory");
    __builtin_amdgcn_s_barrier();
    if (wj == 0 && lg == 0) {
        const int ip = i0 + G_ - 1;
        const float2 pp = Ppart[(G_ - 1) & 1][wf][lm];
        const float2 sr = S2[s2i(b, ip >> 4, ip & 3, (ip >> 2) & 3, fbp)];
        float2 o;
        o.x = osum_prev0 + pp.x + sr.x;
        o.y = osum_prev1 + pp.y + sr.y;
        *(float2*)(out + (size_t)(b * N_ + ip) * F_ + fb) = o;
    }
}

extern "C" void kernel_launch(void* const* d_in, const int* in_sizes, int n_in,
                              void* d_out, int out_size, void* d_ws, size_t ws_size,
                              hipStream_t stream) {
    const float*    inputs  = (const float*)d_in[0];
    const unsigned* adjw    = (const unsigned*)d_in[1];
    const float*    op_emb  = (const float*)d_in[2];
    const float*    weight  = (const float*)d_in[3];
    const float*    attn_w  = (const float*)d_in[4];
    const float*    attn_b  = (const float*)d_in[5];
    const float*    self_op = (const float*)d_in[6];
    float* out = (float*)d_out;
    float2* S2 = (float2*)d_ws;  // fragment-layout support, 3,145,728 bytes

    support_kernel<<<(B_ * N_) / 16, 256, 0, stream>>>(inputs, weight, S2);
    fused_kernel<<<B_ * NGRP, 512, 0, stream>>>(op_emb, adjw, attn_w, attn_b, self_op,
                                                S2, out);
}